// Round 3
// baseline (2256.859 us; speedup 1.0000x reference)
//
#include <hip/hip_runtime.h>
#include <hip/hip_bf16.h>

#define NN 100000
#define EE 1600000
#define GG 256
#define SLOPE 0.01f

__device__ __forceinline__ float leaky(float x) { return x > 0.f ? x : SLOPE * x; }

// ---------- generic ----------
__global__ void fill_kernel(float* p, float v, int n) {
    int i = blockIdx.x * blockDim.x + threadIdx.x, s = gridDim.x * blockDim.x;
    for (; i < n; i += s) p[i] = v;
}

// ---------- normalization ----------
__global__ void deg_accum(const int* __restrict__ dst, const float* __restrict__ ew,
                          float* __restrict__ deg) {
    int e = blockIdx.x * blockDim.x + threadIdx.x, s = gridDim.x * blockDim.x;
    for (; e < EE; e += s) atomicAdd(&deg[dst[e]], ew[e]);
}

__global__ void dis_selfn_kernel(const float* __restrict__ deg, float* __restrict__ dis,
                                 float* __restrict__ selfn) {
    int i = blockIdx.x * blockDim.x + threadIdx.x, s = gridDim.x * blockDim.x;
    for (; i < NN; i += s) {
        float r = rsqrtf(deg[i]);  // deg >= 1 (self-loop weight baked in), no zero guard needed
        dis[i] = r;
        selfn[i] = r * r;
    }
}

__global__ void norm_kernel(const int* __restrict__ src, const int* __restrict__ dst,
                            const float* __restrict__ ew, const float* __restrict__ dis,
                            float* __restrict__ nrm) {
    int e = blockIdx.x * blockDim.x + threadIdx.x, s = gridDim.x * blockDim.x;
    for (; e < EE; e += s) nrm[e] = dis[src[e]] * ew[e] * dis[dst[e]];
}

// ---------- propagation F=3 ----------
__global__ void init_self3(const float* __restrict__ xin, const float* __restrict__ selfn,
                           float* __restrict__ xout) {
    int i = blockIdx.x * blockDim.x + threadIdx.x, s = gridDim.x * blockDim.x;
    for (; i < NN; i += s) {
        float sv = selfn[i];
        xout[i * 3 + 0] = sv * xin[i * 3 + 0];
        xout[i * 3 + 1] = sv * xin[i * 3 + 1];
        xout[i * 3 + 2] = sv * xin[i * 3 + 2];
    }
}

__global__ void scatter3(const int* __restrict__ src, const int* __restrict__ dst,
                         const float* __restrict__ nrm, const float* __restrict__ xin,
                         float* __restrict__ xout) {
    int e = blockIdx.x * blockDim.x + threadIdx.x, s = gridDim.x * blockDim.x;
    for (; e < EE; e += s) {
        int sn = src[e], dn = dst[e];
        float w = nrm[e];
        atomicAdd(&xout[dn * 3 + 0], w * xin[sn * 3 + 0]);
        atomicAdd(&xout[dn * 3 + 1], w * xin[sn * 3 + 1]);
        atomicAdd(&xout[dn * 3 + 2], w * xin[sn * 3 + 2]);
    }
}

// ---------- propagation F=64 ----------
__global__ void init_self64(const float* __restrict__ xin, const float* __restrict__ selfn,
                            float* __restrict__ xout) {
    int i = blockIdx.x * blockDim.x + threadIdx.x, s = gridDim.x * blockDim.x;
    for (; i < NN * 64; i += s) xout[i] = selfn[i >> 6] * xin[i];
}

// one wave (64 lanes) per edge; lane = feature
__global__ void scatter64(const int* __restrict__ src, const int* __restrict__ dst,
                          const float* __restrict__ nrm, const float* __restrict__ xin,
                          float* __restrict__ xout) {
    int wid = (int)((blockIdx.x * (unsigned)blockDim.x + threadIdx.x) >> 6);
    int lane = threadIdx.x & 63;
    if (wid >= EE) return;
    int sn = src[wid], dn = dst[wid];
    float w = nrm[wid];
    atomicAdd(&xout[dn * 64 + lane], w * xin[sn * 64 + lane]);
}

// ---------- layer 1 fused output: h = leaky(b + sum_k x_k @ w_k), x_k are [N][3] ----------
__global__ __launch_bounds__(256) void l1_out(const float* __restrict__ x0, const float* __restrict__ x1,
                                              const float* __restrict__ x2, const float* __restrict__ x3,
                                              const float* __restrict__ w, const float* __restrict__ b,
                                              float* __restrict__ h) {
    __shared__ float wl[4 * 3 * 64];
    __shared__ float bl[64];
    for (int t = threadIdx.x; t < 768; t += 256) wl[t] = w[t];
    if (threadIdx.x < 64) bl[threadIdx.x] = b[threadIdx.x];
    __syncthreads();
    int lane = threadIdx.x & 63;
    int nodeBase = blockIdx.x * 32 + (threadIdx.x >> 6) * 8;  // N=100000 = 3125*32 exactly
    const float* xs[4] = {x0, x1, x2, x3};
#pragma unroll
    for (int r = 0; r < 8; r++) {
        int node = nodeBase + r;
        float acc = bl[lane];
#pragma unroll
        for (int k = 0; k < 4; k++) {
            const float* xp = xs[k] + node * 3;
            acc += xp[0] * wl[k * 192 + lane] + xp[1] * wl[k * 192 + 64 + lane] +
                   xp[2] * wl[k * 192 + 128 + lane];
        }
        h[node * 64 + lane] = leaky(acc);
    }
}

// ---------- layer 2 fused output: out = leaky(b + sum_k h_k @ w_k), h_k are [N][64] ----------
// NOTE: out may alias h0 — each block reads only its own 32 rows (all reads precede writes
// within each owning thread), so the aliasing is race-free.
__global__ __launch_bounds__(256) void l2_out(const float* __restrict__ h0, const float* __restrict__ h1,
                                              const float* __restrict__ h2, const float* __restrict__ h3,
                                              const float* __restrict__ w, const float* __restrict__ b,
                                              float* out) {
    __shared__ float wl[4 * 64 * 64];  // 64 KiB
    for (int t = threadIdx.x; t < 16384; t += 256) wl[t] = w[t];
    __syncthreads();
    int lane = threadIdx.x & 63;
    int nodeBase = blockIdx.x * 32 + (threadIdx.x >> 6) * 8;
    const float* xs[4] = {h0, h1, h2, h3};
    float bias = b[lane];
    float acc[8];
#pragma unroll
    for (int r = 0; r < 8; r++) acc[r] = bias;
#pragma unroll
    for (int k = 0; k < 4; k++) {
        const float* xp = xs[k] + (size_t)nodeBase * 64;
        for (int j4 = 0; j4 < 64; j4 += 4) {
            float4 xv[8];
#pragma unroll
            for (int r = 0; r < 8; r++) xv[r] = *(const float4*)(xp + r * 64 + j4);
#pragma unroll
            for (int jj = 0; jj < 4; jj++) {
                float wv = wl[(k * 64 + j4 + jj) * 64 + lane];
#pragma unroll
                for (int r = 0; r < 8; r++)
                    acc[r] += ((const float*)&xv[r])[jj] * wv;
            }
        }
    }
#pragma unroll
    for (int r = 0; r < 8; r++) out[(size_t)(nodeBase + r) * 64 + lane] = leaky(acc[r]);
}

// ---------- pooling (Batching is sorted) ----------
#define PWAVES 2048
#define NPW ((NN + PWAVES - 1) / PWAVES)  // 49
__global__ void pool_kernel(const float* __restrict__ h, const int* __restrict__ batching,
                            float* __restrict__ pooled, float* __restrict__ cnt) {
    int wid = (int)((blockIdx.x * (unsigned)blockDim.x + threadIdx.x) >> 6);
    int lane = threadIdx.x & 63;
    int start = wid * NPW;
    if (start >= NN) return;
    int end = min(start + NPW, NN);
    int g = batching[start];
    float acc = 0.f, c = 0.f;
    for (int i = start; i < end; i++) {
        int gi = batching[i];
        if (gi != g) {
            atomicAdd(&pooled[g * 64 + lane], acc);
            if (lane == 0) atomicAdd(&cnt[g], c);
            g = gi; acc = 0.f; c = 0.f;
        }
        acc += h[(size_t)i * 64 + lane];
        c += 1.f;
    }
    atomicAdd(&pooled[g * 64 + lane], acc);
    if (lane == 0) atomicAdd(&cnt[g], c);
}

// ---------- heads: two 64->64->64->2 MLPs per graph ----------
__global__ void head_kernel(const float* __restrict__ pooled, const float* __restrict__ cnt,
                            const float* pw1, const float* pb1, const float* pw2, const float* pb2,
                            const float* pw3, const float* pb3,
                            const float* tw1, const float* tb1, const float* tw2, const float* tb2,
                            const float* tw3, const float* tb3,
                            float* __restrict__ out) {
    int g = blockIdx.x, f = threadIdx.x;  // 64 threads
    __shared__ float pm[64], t1[64], t2[64];
    float c = cnt[g];
    if (c < 1.f) c = 1.f;
    pm[f] = pooled[g * 64 + f] / c;
    __syncthreads();
    float a = pb1[f];
    for (int j = 0; j < 64; j++) a += pm[j] * pw1[j * 64 + f];
    t1[f] = leaky(a);
    __syncthreads();
    a = pb2[f];
    for (int j = 0; j < 64; j++) a += t1[j] * pw2[j * 64 + f];
    t2[f] = leaky(a);
    __syncthreads();
    if (f < 2) {
        float o = pb3[f];
        for (int j = 0; j < 64; j++) o += t2[j] * pw3[j * 2 + f];
        out[g * 4 + f] = o;
    }
    __syncthreads();
    a = tb1[f];
    for (int j = 0; j < 64; j++) a += pm[j] * tw1[j * 64 + f];
    t1[f] = leaky(a);
    __syncthreads();
    a = tb2[f];
    for (int j = 0; j < 64; j++) a += t1[j] * tw2[j * 64 + f];
    t2[f] = leaky(a);
    __syncthreads();
    if (f < 2) {
        float o = tb3[f];
        for (int j = 0; j < 64; j++) o += t2[j] * tw3[j * 2 + f];
        out[g * 4 + 2 + f] = o;
    }
}

extern "C" void kernel_launch(void* const* d_in, const int* in_sizes, int n_in,
                              void* d_out, int out_size, void* d_ws, size_t ws_size,
                              hipStream_t stream) {
    const float* X = (const float*)d_in[0];
    const int* ei = (const int*)d_in[1];  // [2][E]
    const float* ew = (const float*)d_in[2];
    const int* batching = (const int*)d_in[3];
    const float* c1w = (const float*)d_in[4];
    const float* c1b = (const float*)d_in[5];
    const float* c2w = (const float*)d_in[6];
    const float* c2b = (const float*)d_in[7];
    const float* pw1 = (const float*)d_in[8];
    const float* pb1 = (const float*)d_in[9];
    const float* pw2 = (const float*)d_in[10];
    const float* pb2 = (const float*)d_in[11];
    const float* pw3 = (const float*)d_in[12];
    const float* pb3 = (const float*)d_in[13];
    const float* tw1 = (const float*)d_in[14];
    const float* tb1 = (const float*)d_in[15];
    const float* tw2 = (const float*)d_in[16];
    const float* tb2 = (const float*)d_in[17];
    const float* tw3 = (const float*)d_in[18];
    const float* tb3 = (const float*)d_in[19];
    float* out = (float*)d_out;

    const int* src = ei;
    const int* dst = ei + EE;

    float* ws = (float*)d_ws;
    float* deg = ws;                       // N
    float* dis = deg + NN;                 // N
    float* selfn = dis + NN;               // N
    float* nrm = selfn + NN;               // E
    float* x1 = nrm + EE;                  // N*3
    float* x2 = x1 + NN * 3;               // N*3
    float* x3 = x2 + NN * 3;               // N*3
    float* h = x3 + NN * 3;                // N*64
    float* h1 = h + (size_t)NN * 64;       // N*64
    float* h2 = h1 + (size_t)NN * 64;      // N*64
    float* h3 = h2 + (size_t)NN * 64;      // N*64
    float* o2 = h;                         // aliased: l2_out is block-local row-wise, safe
    float* pooled = h3 + (size_t)NN * 64;  // G*64
    float* cnt = pooled + GG * 64;         // G

    // init
    fill_kernel<<<512, 256, 0, stream>>>(deg, 1.0f, NN);  // self-loop weight 1 baked in
    fill_kernel<<<64, 256, 0, stream>>>(pooled, 0.0f, GG * 64 + GG);

    // gcn_norm
    deg_accum<<<2048, 256, 0, stream>>>(dst, ew, deg);
    dis_selfn_kernel<<<512, 256, 0, stream>>>(deg, dis, selfn);
    norm_kernel<<<2048, 256, 0, stream>>>(src, dst, ew, dis, nrm);

    // layer 1 hops (F=3)
    init_self3<<<512, 256, 0, stream>>>(X, selfn, x1);
    scatter3<<<2048, 256, 0, stream>>>(src, dst, nrm, X, x1);
    init_self3<<<512, 256, 0, stream>>>(x1, selfn, x2);
    scatter3<<<2048, 256, 0, stream>>>(src, dst, nrm, x1, x2);
    init_self3<<<512, 256, 0, stream>>>(x2, selfn, x3);
    scatter3<<<2048, 256, 0, stream>>>(src, dst, nrm, x2, x3);
    l1_out<<<NN / 32, 256, 0, stream>>>(X, x1, x2, x3, c1w, c1b, h);

    // layer 2 hops (F=64)
    init_self64<<<2048, 256, 0, stream>>>(h, selfn, h1);
    scatter64<<<EE / 4, 256, 0, stream>>>(src, dst, nrm, h, h1);
    init_self64<<<2048, 256, 0, stream>>>(h1, selfn, h2);
    scatter64<<<EE / 4, 256, 0, stream>>>(src, dst, nrm, h1, h2);
    init_self64<<<2048, 256, 0, stream>>>(h2, selfn, h3);
    scatter64<<<EE / 4, 256, 0, stream>>>(src, dst, nrm, h2, h3);
    l2_out<<<NN / 32, 256, 0, stream>>>(h, h1, h2, h3, c2w, c2b, o2);

    // pool + heads
    pool_kernel<<<PWAVES / 4, 256, 0, stream>>>(o2, batching, pooled, cnt);
    head_kernel<<<GG, 64, 0, stream>>>(pooled, cnt, pw1, pb1, pw2, pb2, pw3, pb3,
                                       tw1, tb1, tw2, tb2, tw3, tb3, out);
}

// Round 4
// 950.920 us; speedup vs baseline: 2.3733x; 2.3733x over previous
//
#include <hip/hip_runtime.h>
#include <hip/hip_bf16.h>

#define NN 100000
#define EE 1600000
#define GG 256
#define SLOPE 0.01f
#define SCAN_BS 1024
#define NBLK ((NN + SCAN_BS - 1) / SCAN_BS)  // 98

__device__ __forceinline__ float leaky(float x) { return x > 0.f ? x : SLOPE * x; }

// ---------- init ----------
__global__ void zero_int_kernel(int* p, int n) {
    int i = blockIdx.x * blockDim.x + threadIdx.x, s = gridDim.x * blockDim.x;
    for (; i < n; i += s) p[i] = 0;
}

__global__ void fill_kernel(float* p, float v, int n) {
    int i = blockIdx.x * blockDim.x + threadIdx.x, s = gridDim.x * blockDim.x;
    for (; i < n; i += s) p[i] = v;
}

// ---------- CSR build (by dst) ----------
__global__ void hist_kernel(const int* __restrict__ dst, int* __restrict__ cnt) {
    int e = blockIdx.x * blockDim.x + threadIdx.x, s = gridDim.x * blockDim.x;
    for (; e < EE; e += s) atomicAdd(&cnt[dst[e]], 1);
}

__global__ __launch_bounds__(1024) void scan_block_kernel(const int* __restrict__ cnt,
                                                          int* __restrict__ rowptr,
                                                          int* __restrict__ blksum) {
    __shared__ int tmp[SCAN_BS];
    int t = threadIdx.x, n = blockIdx.x * SCAN_BS + t;
    int v = (n < NN) ? cnt[n] : 0;
    tmp[t] = v;
    __syncthreads();
    for (int off = 1; off < SCAN_BS; off <<= 1) {
        int a = (t >= off) ? tmp[t - off] : 0;
        __syncthreads();
        tmp[t] += a;
        __syncthreads();
    }
    if (n < NN) rowptr[n] = tmp[t] - v;  // block-local exclusive prefix
    if (t == SCAN_BS - 1) blksum[blockIdx.x] = tmp[t];
}

__global__ void scan_top_kernel(int* __restrict__ blksum) {  // 1 block, 128 threads
    __shared__ int tmp[128];
    int t = threadIdx.x;
    int v = (t < NBLK) ? blksum[t] : 0;
    tmp[t] = v;
    __syncthreads();
    for (int off = 1; off < 128; off <<= 1) {
        int a = (t >= off) ? tmp[t - off] : 0;
        __syncthreads();
        tmp[t] += a;
        __syncthreads();
    }
    if (t < NBLK) blksum[t] = tmp[t] - v;  // exclusive
}

__global__ void scan_add_kernel(int* __restrict__ rowptr, const int* __restrict__ blksum,
                                int* __restrict__ cursor) {
    int n = blockIdx.x * blockDim.x + threadIdx.x, s = gridDim.x * blockDim.x;
    for (; n < NN; n += s) {
        int r = rowptr[n] + blksum[n / SCAN_BS];
        rowptr[n] = r;
        cursor[n] = r;
    }
    if (blockIdx.x == 0 && threadIdx.x == 0) rowptr[NN] = EE;
}

__global__ void build_kernel(const int* __restrict__ src, const int* __restrict__ dst,
                             const float* __restrict__ ew, int* __restrict__ cursor,
                             float2* __restrict__ pairs) {
    int e = blockIdx.x * blockDim.x + threadIdx.x, s = gridDim.x * blockDim.x;
    for (; e < EE; e += s) {
        int pos = atomicAdd(&cursor[dst[e]], 1);
        pairs[pos] = make_float2(__int_as_float(src[e]), ew[e]);
    }
}

// ---------- normalization over CSR ----------
__global__ void node_dis_kernel(const int* __restrict__ rowptr, const float2* __restrict__ pairs,
                                float* __restrict__ dis, float* __restrict__ selfn) {
    int n = blockIdx.x * blockDim.x + threadIdx.x;
    if (n >= NN) return;
    int b = rowptr[n], e2 = rowptr[n + 1];
    float s = 1.0f;  // self-loop weight
    for (int i = b; i < e2; i++) s += pairs[i].y;
    float r = rsqrtf(s);
    dis[n] = r;
    selfn[n] = r * r;  // = 1/deg
}

__global__ void node_nrm_kernel(const int* __restrict__ rowptr, float2* __restrict__ pairs,
                                const float* __restrict__ dis) {
    int n = blockIdx.x * blockDim.x + threadIdx.x;
    if (n >= NN) return;
    int b = rowptr[n], e2 = rowptr[n + 1];
    float dn = dis[n];
    for (int i = b; i < e2; i++) {
        float2 p = pairs[i];
        p.y = dis[__float_as_int(p.x)] * p.y * dn;
        pairs[i] = p;
    }
}

// ---------- propagation F=3 (thread per node, self-term fused) ----------
__global__ void gather3_kernel(const int* __restrict__ rowptr, const float2* __restrict__ pairs,
                               const float* __restrict__ selfn, const float* __restrict__ xin,
                               float* __restrict__ xout) {
    int n = blockIdx.x * blockDim.x + threadIdx.x;
    if (n >= NN) return;
    int b = rowptr[n], e2 = rowptr[n + 1];
    float sv = selfn[n];
    float a0 = sv * xin[n * 3 + 0], a1 = sv * xin[n * 3 + 1], a2 = sv * xin[n * 3 + 2];
    for (int i = b; i < e2; i++) {
        float2 p = pairs[i];
        int s3 = __float_as_int(p.x) * 3;
        a0 += p.y * xin[s3 + 0];
        a1 += p.y * xin[s3 + 1];
        a2 += p.y * xin[s3 + 2];
    }
    xout[n * 3 + 0] = a0;
    xout[n * 3 + 1] = a1;
    xout[n * 3 + 2] = a2;
}

// ---------- propagation F=64 (wave per node, lane = feature, no atomics) ----------
__global__ __launch_bounds__(256) void gather64_kernel(const int* __restrict__ rowptr,
                                                       const float2* __restrict__ pairs,
                                                       const float* __restrict__ selfn,
                                                       const float* __restrict__ xin,
                                                       float* __restrict__ xout) {
    int wid = (int)((blockIdx.x * (unsigned)blockDim.x + threadIdx.x) >> 6);
    int lane = threadIdx.x & 63;
    if (wid >= NN) return;
    int b = rowptr[wid], e2 = rowptr[wid + 1];
    float acc = selfn[wid] * xin[(size_t)wid * 64 + lane];
    int i = b;
    for (; i + 1 < e2; i += 2) {  // unroll 2 for load ILP
        float2 p0 = pairs[i], p1 = pairs[i + 1];
        float v0 = xin[(size_t)__float_as_int(p0.x) * 64 + lane];
        float v1 = xin[(size_t)__float_as_int(p1.x) * 64 + lane];
        acc += p0.y * v0 + p1.y * v1;
    }
    if (i < e2) {
        float2 p = pairs[i];
        acc += p.y * xin[(size_t)__float_as_int(p.x) * 64 + lane];
    }
    xout[(size_t)wid * 64 + lane] = acc;
}

// ---------- layer 1 fused output: h = leaky(b + sum_k x_k @ w_k), x_k are [N][3] ----------
__global__ __launch_bounds__(256) void l1_out(const float* __restrict__ x0, const float* __restrict__ x1,
                                              const float* __restrict__ x2, const float* __restrict__ x3,
                                              const float* __restrict__ w, const float* __restrict__ b,
                                              float* __restrict__ h) {
    __shared__ float wl[4 * 3 * 64];
    __shared__ float bl[64];
    for (int t = threadIdx.x; t < 768; t += 256) wl[t] = w[t];
    if (threadIdx.x < 64) bl[threadIdx.x] = b[threadIdx.x];
    __syncthreads();
    int lane = threadIdx.x & 63;
    int nodeBase = blockIdx.x * 32 + (threadIdx.x >> 6) * 8;  // N=100000 = 3125*32 exactly
    const float* xs[4] = {x0, x1, x2, x3};
#pragma unroll
    for (int r = 0; r < 8; r++) {
        int node = nodeBase + r;
        float acc = bl[lane];
#pragma unroll
        for (int k = 0; k < 4; k++) {
            const float* xp = xs[k] + node * 3;
            acc += xp[0] * wl[k * 192 + lane] + xp[1] * wl[k * 192 + 64 + lane] +
                   xp[2] * wl[k * 192 + 128 + lane];
        }
        h[node * 64 + lane] = leaky(acc);
    }
}

// ---------- layer 2 fused output: out = leaky(b + sum_k h_k @ w_k), h_k are [N][64] ----------
// out may alias h0: each block reads only its own 32 rows; reads precede writes per thread.
__global__ __launch_bounds__(256) void l2_out(const float* __restrict__ h0, const float* __restrict__ h1,
                                              const float* __restrict__ h2, const float* __restrict__ h3,
                                              const float* __restrict__ w, const float* __restrict__ b,
                                              float* out) {
    __shared__ float wl[4 * 64 * 64];  // 64 KiB
    for (int t = threadIdx.x; t < 16384; t += 256) wl[t] = w[t];
    __syncthreads();
    int lane = threadIdx.x & 63;
    int nodeBase = blockIdx.x * 32 + (threadIdx.x >> 6) * 8;
    const float* xs[4] = {h0, h1, h2, h3};
    float bias = b[lane];
    float acc[8];
#pragma unroll
    for (int r = 0; r < 8; r++) acc[r] = bias;
#pragma unroll
    for (int k = 0; k < 4; k++) {
        const float* xp = xs[k] + (size_t)nodeBase * 64;
        for (int j4 = 0; j4 < 64; j4 += 4) {
            float4 xv[8];
#pragma unroll
            for (int r = 0; r < 8; r++) xv[r] = *(const float4*)(xp + r * 64 + j4);
#pragma unroll
            for (int jj = 0; jj < 4; jj++) {
                float wv = wl[(k * 64 + j4 + jj) * 64 + lane];
#pragma unroll
                for (int r = 0; r < 8; r++)
                    acc[r] += ((const float*)&xv[r])[jj] * wv;
            }
        }
    }
#pragma unroll
    for (int r = 0; r < 8; r++) out[(size_t)(nodeBase + r) * 64 + lane] = leaky(acc[r]);
}

// ---------- pooling (Batching is sorted) ----------
#define PWAVES 2048
#define NPW ((NN + PWAVES - 1) / PWAVES)  // 49
__global__ void pool_kernel(const float* __restrict__ h, const int* __restrict__ batching,
                            float* __restrict__ pooled, float* __restrict__ cnt) {
    int wid = (int)((blockIdx.x * (unsigned)blockDim.x + threadIdx.x) >> 6);
    int lane = threadIdx.x & 63;
    int start = wid * NPW;
    if (start >= NN) return;
    int end = min(start + NPW, NN);
    int g = batching[start];
    float acc = 0.f, c = 0.f;
    for (int i = start; i < end; i++) {
        int gi = batching[i];
        if (gi != g) {
            atomicAdd(&pooled[g * 64 + lane], acc);
            if (lane == 0) atomicAdd(&cnt[g], c);
            g = gi; acc = 0.f; c = 0.f;
        }
        acc += h[(size_t)i * 64 + lane];
        c += 1.f;
    }
    atomicAdd(&pooled[g * 64 + lane], acc);
    if (lane == 0) atomicAdd(&cnt[g], c);
}

// ---------- heads: two 64->64->64->2 MLPs per graph ----------
__global__ void head_kernel(const float* __restrict__ pooled, const float* __restrict__ cnt,
                            const float* pw1, const float* pb1, const float* pw2, const float* pb2,
                            const float* pw3, const float* pb3,
                            const float* tw1, const float* tb1, const float* tw2, const float* tb2,
                            const float* tw3, const float* tb3,
                            float* __restrict__ out) {
    int g = blockIdx.x, f = threadIdx.x;  // 64 threads
    __shared__ float pm[64], t1[64], t2[64];
    float c = cnt[g];
    if (c < 1.f) c = 1.f;
    pm[f] = pooled[g * 64 + f] / c;
    __syncthreads();
    float a = pb1[f];
    for (int j = 0; j < 64; j++) a += pm[j] * pw1[j * 64 + f];
    t1[f] = leaky(a);
    __syncthreads();
    a = pb2[f];
    for (int j = 0; j < 64; j++) a += t1[j] * pw2[j * 64 + f];
    t2[f] = leaky(a);
    __syncthreads();
    if (f < 2) {
        float o = pb3[f];
        for (int j = 0; j < 64; j++) o += t2[j] * pw3[j * 2 + f];
        out[g * 4 + f] = o;
    }
    __syncthreads();
    a = tb1[f];
    for (int j = 0; j < 64; j++) a += pm[j] * tw1[j * 64 + f];
    t1[f] = leaky(a);
    __syncthreads();
    a = tb2[f];
    for (int j = 0; j < 64; j++) a += t1[j] * tw2[j * 64 + f];
    t2[f] = leaky(a);
    __syncthreads();
    if (f < 2) {
        float o = tb3[f];
        for (int j = 0; j < 64; j++) o += t2[j] * tw3[j * 2 + f];
        out[g * 4 + 2 + f] = o;
    }
}

extern "C" void kernel_launch(void* const* d_in, const int* in_sizes, int n_in,
                              void* d_out, int out_size, void* d_ws, size_t ws_size,
                              hipStream_t stream) {
    const float* X = (const float*)d_in[0];
    const int* ei = (const int*)d_in[1];  // [2][E]
    const float* ew = (const float*)d_in[2];
    const int* batching = (const int*)d_in[3];
    const float* c1w = (const float*)d_in[4];
    const float* c1b = (const float*)d_in[5];
    const float* c2w = (const float*)d_in[6];
    const float* c2b = (const float*)d_in[7];
    const float* pw1 = (const float*)d_in[8];
    const float* pb1 = (const float*)d_in[9];
    const float* pw2 = (const float*)d_in[10];
    const float* pb2 = (const float*)d_in[11];
    const float* pw3 = (const float*)d_in[12];
    const float* pb3 = (const float*)d_in[13];
    const float* tw1 = (const float*)d_in[14];
    const float* tb1 = (const float*)d_in[15];
    const float* tw2 = (const float*)d_in[16];
    const float* tb2 = (const float*)d_in[17];
    const float* tw3 = (const float*)d_in[18];
    const float* tb3 = (const float*)d_in[19];
    float* out = (float*)d_out;

    const int* src = ei;
    const int* dst = ei + EE;

    // ---- workspace layout ----
    char* base = (char*)d_ws;
    int* cnt = (int*)base;                 // NN
    int* rowptr = cnt + NN;                // NN+1
    int* cursor = rowptr + NN + 1;         // NN
    int* blksum = cursor + NN;             // NBLK (98)
    size_t off = ((size_t)(3 * NN + 1 + NBLK) * 4 + 7) & ~(size_t)7;
    float2* pairs = (float2*)(base + off);     // EE  (12.8 MB)
    float* dis = (float*)(pairs + EE);         // NN
    float* selfn = dis + NN;                   // NN
    float* x1 = selfn + NN;                    // NN*3
    float* x2 = x1 + NN * 3;                   // NN*3
    float* x3 = x2 + NN * 3;                   // NN*3
    float* h = x3 + NN * 3;                    // NN*64
    float* h1 = h + (size_t)NN * 64;           // NN*64
    float* h2 = h1 + (size_t)NN * 64;          // NN*64
    float* h3 = h2 + (size_t)NN * 64;          // NN*64
    float* o2 = h;                             // aliased (block-local rows, safe)
    float* pooled = h3 + (size_t)NN * 64;      // GG*64
    float* cntf = pooled + GG * 64;            // GG

    // ---- init ----
    zero_int_kernel<<<512, 256, 0, stream>>>(cnt, NN);
    fill_kernel<<<64, 256, 0, stream>>>(pooled, 0.0f, GG * 64 + GG);

    // ---- CSR build (by dst) ----
    hist_kernel<<<2048, 256, 0, stream>>>(dst, cnt);
    scan_block_kernel<<<NBLK, SCAN_BS, 0, stream>>>(cnt, rowptr, blksum);
    scan_top_kernel<<<1, 128, 0, stream>>>(blksum);
    scan_add_kernel<<<392, 256, 0, stream>>>(rowptr, blksum, cursor);
    build_kernel<<<2048, 256, 0, stream>>>(src, dst, ew, cursor, pairs);

    // ---- gcn_norm over CSR ----
    node_dis_kernel<<<392, 256, 0, stream>>>(rowptr, pairs, dis, selfn);
    node_nrm_kernel<<<392, 256, 0, stream>>>(rowptr, pairs, dis);

    // ---- layer 1 hops (F=3) ----
    gather3_kernel<<<392, 256, 0, stream>>>(rowptr, pairs, selfn, X, x1);
    gather3_kernel<<<392, 256, 0, stream>>>(rowptr, pairs, selfn, x1, x2);
    gather3_kernel<<<392, 256, 0, stream>>>(rowptr, pairs, selfn, x2, x3);
    l1_out<<<NN / 32, 256, 0, stream>>>(X, x1, x2, x3, c1w, c1b, h);

    // ---- layer 2 hops (F=64) ----
    gather64_kernel<<<25000, 256, 0, stream>>>(rowptr, pairs, selfn, h, h1);
    gather64_kernel<<<25000, 256, 0, stream>>>(rowptr, pairs, selfn, h1, h2);
    gather64_kernel<<<25000, 256, 0, stream>>>(rowptr, pairs, selfn, h2, h3);
    l2_out<<<NN / 32, 256, 0, stream>>>(h, h1, h2, h3, c2w, c2b, o2);

    // ---- pool + heads ----
    pool_kernel<<<PWAVES / 4, 256, 0, stream>>>(o2, batching, pooled, cntf);
    head_kernel<<<GG, 64, 0, stream>>>(pooled, cntf, pw1, pb1, pw2, pb2, pw3, pb3,
                                       tw1, tb1, tw2, tb2, tw3, tb3, out);
}

// Round 6
// 648.477 us; speedup vs baseline: 3.4802x; 1.4664x over previous
//
#include <hip/hip_runtime.h>
#include <hip/hip_bf16.h>

#define NN 100000
#define EE 1600000
#define GG 256
#define SLOPE 0.01f
#define SCAN_BS 1024
#define NBLK ((NN + SCAN_BS - 1) / SCAN_BS)  // 98

typedef __hip_bfloat16 bf16;
typedef __attribute__((ext_vector_type(8))) short s16x8;
typedef __attribute__((ext_vector_type(4))) float f32x4;

__device__ __forceinline__ float leaky(float x) { return x > 0.f ? x : SLOPE * x; }
__device__ __forceinline__ float bf2f(bf16 v) { return __bfloat162float(v); }

// ---------- init ----------
__global__ void zero_int_kernel(int* p, int n) {
    int i = blockIdx.x * blockDim.x + threadIdx.x, s = gridDim.x * blockDim.x;
    for (; i < n; i += s) p[i] = 0;
}

__global__ void fill_kernel(float* p, float v, int n) {
    int i = blockIdx.x * blockDim.x + threadIdx.x, s = gridDim.x * blockDim.x;
    for (; i < n; i += s) p[i] = v;
}

// ---------- CSR build (by dst) ----------
__global__ void hist_kernel(const int* __restrict__ dst, int* __restrict__ cnt) {
    int e = blockIdx.x * blockDim.x + threadIdx.x, s = gridDim.x * blockDim.x;
    for (; e < EE; e += s) atomicAdd(&cnt[dst[e]], 1);
}

__global__ __launch_bounds__(1024) void scan_block_kernel(const int* __restrict__ cnt,
                                                          int* __restrict__ rowptr,
                                                          int* __restrict__ blksum) {
    __shared__ int tmp[SCAN_BS];
    int t = threadIdx.x, n = blockIdx.x * SCAN_BS + t;
    int v = (n < NN) ? cnt[n] : 0;
    tmp[t] = v;
    __syncthreads();
    for (int off = 1; off < SCAN_BS; off <<= 1) {
        int a = (t >= off) ? tmp[t - off] : 0;
        __syncthreads();
        tmp[t] += a;
        __syncthreads();
    }
    if (n < NN) rowptr[n] = tmp[t] - v;  // block-local exclusive prefix
    if (t == SCAN_BS - 1) blksum[blockIdx.x] = tmp[t];
}

__global__ void scan_top_kernel(int* __restrict__ blksum) {  // 1 block, 128 threads
    __shared__ int tmp[128];
    int t = threadIdx.x;
    int v = (t < NBLK) ? blksum[t] : 0;
    tmp[t] = v;
    __syncthreads();
    for (int off = 1; off < 128; off <<= 1) {
        int a = (t >= off) ? tmp[t - off] : 0;
        __syncthreads();
        tmp[t] += a;
        __syncthreads();
    }
    if (t < NBLK) blksum[t] = tmp[t] - v;  // exclusive
}

__global__ void scan_add_kernel(int* __restrict__ rowptr, const int* __restrict__ blksum,
                                int* __restrict__ cursor) {
    int n = blockIdx.x * blockDim.x + threadIdx.x, s = gridDim.x * blockDim.x;
    for (; n < NN; n += s) {
        int r = rowptr[n] + blksum[n / SCAN_BS];
        rowptr[n] = r;
        cursor[n] = r;
    }
    if (blockIdx.x == 0 && threadIdx.x == 0) rowptr[NN] = EE;
}

__global__ void build_kernel(const int* __restrict__ src, const int* __restrict__ dst,
                             const float* __restrict__ ew, int* __restrict__ cursor,
                             float2* __restrict__ pairs) {
    int e = blockIdx.x * blockDim.x + threadIdx.x, s = gridDim.x * blockDim.x;
    for (; e < EE; e += s) {
        int pos = atomicAdd(&cursor[dst[e]], 1);
        pairs[pos] = make_float2(__int_as_float(src[e]), ew[e]);
    }
}

// ---------- normalization over CSR ----------
__global__ void node_dis_kernel(const int* __restrict__ rowptr, const float2* __restrict__ pairs,
                                float* __restrict__ dis, float* __restrict__ selfn) {
    int n = blockIdx.x * blockDim.x + threadIdx.x;
    if (n >= NN) return;
    int b = rowptr[n], e2 = rowptr[n + 1];
    float s = 1.0f;  // self-loop weight
    for (int i = b; i < e2; i++) s += pairs[i].y;
    float r = rsqrtf(s);
    dis[n] = r;
    selfn[n] = r * r;  // = 1/deg
}

__global__ void node_nrm_kernel(const int* __restrict__ rowptr, float2* __restrict__ pairs,
                                const float* __restrict__ dis) {
    int n = blockIdx.x * blockDim.x + threadIdx.x;
    if (n >= NN) return;
    int b = rowptr[n], e2 = rowptr[n + 1];
    float dn = dis[n];
    for (int i = b; i < e2; i++) {
        float2 p = pairs[i];
        p.y = dis[__float_as_int(p.x)] * p.y * dn;
        pairs[i] = p;
    }
}

// ---------- propagation F=3 (thread per node, self-term fused, f32) ----------
__global__ void gather3_kernel(const int* __restrict__ rowptr, const float2* __restrict__ pairs,
                               const float* __restrict__ selfn, const float* __restrict__ xin,
                               float* __restrict__ xout) {
    int n = blockIdx.x * blockDim.x + threadIdx.x;
    if (n >= NN) return;
    int b = rowptr[n], e2 = rowptr[n + 1];
    float sv = selfn[n];
    float a0 = sv * xin[n * 3 + 0], a1 = sv * xin[n * 3 + 1], a2 = sv * xin[n * 3 + 2];
    for (int i = b; i < e2; i++) {
        float2 p = pairs[i];
        int s3 = __float_as_int(p.x) * 3;
        a0 += p.y * xin[s3 + 0];
        a1 += p.y * xin[s3 + 1];
        a2 += p.y * xin[s3 + 2];
    }
    xout[n * 3 + 0] = a0;
    xout[n * 3 + 1] = a1;
    xout[n * 3 + 2] = a2;
}

// ---------- propagation F=64 over bf16 rows (wave per node, lane = feature) ----------
__global__ __launch_bounds__(256) void gather64b_kernel(const int* __restrict__ rowptr,
                                                        const float2* __restrict__ pairs,
                                                        const float* __restrict__ selfn,
                                                        const bf16* __restrict__ xin,
                                                        bf16* __restrict__ xout) {
    int wid = (int)((blockIdx.x * (unsigned)blockDim.x + threadIdx.x) >> 6);
    int lane = threadIdx.x & 63;
    if (wid >= NN) return;
    int b = rowptr[wid], e2 = rowptr[wid + 1];
    float acc = selfn[wid] * bf2f(xin[wid * 64 + lane]);
    int i = b;
    for (; i + 3 < e2; i += 4) {  // unroll 4: MLP for the latency-bound gathers
        float2 p0 = pairs[i], p1 = pairs[i + 1], p2 = pairs[i + 2], p3 = pairs[i + 3];
        float v0 = bf2f(xin[__float_as_int(p0.x) * 64 + lane]);
        float v1 = bf2f(xin[__float_as_int(p1.x) * 64 + lane]);
        float v2 = bf2f(xin[__float_as_int(p2.x) * 64 + lane]);
        float v3 = bf2f(xin[__float_as_int(p3.x) * 64 + lane]);
        acc += p0.y * v0 + p1.y * v1 + p2.y * v2 + p3.y * v3;
    }
    for (; i < e2; i++) {
        float2 p = pairs[i];
        acc += p.y * bf2f(xin[__float_as_int(p.x) * 64 + lane]);
    }
    xout[wid * 64 + lane] = __float2bfloat16(acc);
}

// ---------- layer 1 fused output: h = leaky(b + sum_k x_k @ w_k) -> bf16 ----------
__global__ __launch_bounds__(256) void l1_out(const float* __restrict__ x0, const float* __restrict__ x1,
                                              const float* __restrict__ x2, const float* __restrict__ x3,
                                              const float* __restrict__ w, const float* __restrict__ b,
                                              bf16* __restrict__ h) {
    __shared__ float wl[4 * 3 * 64];
    __shared__ float bl[64];
    for (int t = threadIdx.x; t < 768; t += 256) wl[t] = w[t];
    if (threadIdx.x < 64) bl[threadIdx.x] = b[threadIdx.x];
    __syncthreads();
    int lane = threadIdx.x & 63;
    int nodeBase = blockIdx.x * 32 + (threadIdx.x >> 6) * 8;  // N = 3125*32 exactly
    const float* xs[4] = {x0, x1, x2, x3};
#pragma unroll
    for (int r = 0; r < 8; r++) {
        int node = nodeBase + r;
        float acc = bl[lane];
#pragma unroll
        for (int k = 0; k < 4; k++) {
            const float* xp = xs[k] + node * 3;
            acc += xp[0] * wl[k * 192 + lane] + xp[1] * wl[k * 192 + 64 + lane] +
                   xp[2] * wl[k * 192 + 128 + lane];
        }
        h[node * 64 + lane] = __float2bfloat16(leaky(acc));
    }
}

// ---------- layer 2 via MFMA: out[n][f] = leaky(b[f] + sum_{hop,j} h_hop[n][j] w[hop][j][f]) ----
// GEMM M=100000, K=256 (4 hops x 64), N=64, bf16 inputs, f32 accum.
// Per block: 4 waves, wave w owns a 16-row tile (block covers 64 nodes); each wave computes
// 16x64 outputs as 4 n-tiles of 16x16 via mfma_f32_16x16x32_bf16 over 8 k-steps.
// A-frag: lane l holds A[l&15][(l>>4)*8 + j]; B-frag: lane l holds B[(l>>4)*8+j][l&15].
// C/D (verified m89): col = lane&15, row = (lane>>4)*4 + reg.
__global__ __launch_bounds__(256) void l2_mfma(const bf16* __restrict__ h0, const bf16* __restrict__ h1,
                                               const bf16* __restrict__ h2, const bf16* __restrict__ h3,
                                               const float* __restrict__ w, const float* __restrict__ b,
                                               float* __restrict__ out) {
    __shared__ bf16 bt[64 * 256];  // BT[n][k], XOR-swizzled, 32 KiB
    __shared__ float bl[64];
    char* btc = (char*)bt;
    // stage W transposed+swizzled: k = hop*64 + j ; BT byte addr = n*512 + ((2k) ^ ((n&7)<<4))
    for (int idx = threadIdx.x; idx < 16384; idx += 256) {
        int hop = idx >> 12, j = (idx >> 6) & 63, n = idx & 63;
        int k = hop * 64 + j;
        bf16 v = __float2bfloat16(w[idx]);
        *(bf16*)(btc + n * 512 + ((k * 2) ^ ((n & 7) << 4))) = v;
    }
    if (threadIdx.x < 64) bl[threadIdx.x] = b[threadIdx.x];
    __syncthreads();

    int lane = threadIdx.x & 63;
    int rbase = blockIdx.x * 64 + (threadIdx.x >> 6) * 16;  // wave's 16-row tile
    if (rbase >= NN) return;
    const bf16* hs[4] = {h0, h1, h2, h3};

    f32x4 acc0 = {0.f, 0.f, 0.f, 0.f}, acc1 = acc0, acc2 = acc0, acc3 = acc0;
    int arow = rbase + (lane & 15);
    int kgrp = (lane >> 4) * 8;  // this lane's k-offset within a 32-k step
#pragma unroll
    for (int ks = 0; ks < 8; ks++) {
        const bf16* hp = hs[ks >> 1];
        s16x8 a = *(const s16x8*)(hp + arow * 64 + (ks & 1) * 32 + kgrp);
        int kbyte = ks * 64 + kgrp * 2;
#pragma unroll
        for (int t = 0; t < 4; t++) {
            int n = t * 16 + (lane & 15);
            s16x8 bb = *(const s16x8*)(btc + n * 512 + (kbyte ^ ((n & 7) << 4)));
            f32x4* ap = (t == 0) ? &acc0 : (t == 1) ? &acc1 : (t == 2) ? &acc2 : &acc3;
            *ap = __builtin_amdgcn_mfma_f32_16x16x32_bf16(a, bb, *ap, 0, 0, 0);
        }
    }
    // epilogue: bias + leaky, f32 store
    int col = lane & 15, rgrp = (lane >> 4) * 4;
#pragma unroll
    for (int t = 0; t < 4; t++) {
        f32x4 a = (t == 0) ? acc0 : (t == 1) ? acc1 : (t == 2) ? acc2 : acc3;
        float bias = bl[t * 16 + col];
#pragma unroll
        for (int r = 0; r < 4; r++) {
            out[(size_t)(rbase + rgrp + r) * 64 + t * 16 + col] = leaky(a[r] + bias);
        }
    }
}

// ---------- pooling (Batching is sorted) ----------
#define PWAVES 2048
#define NPW ((NN + PWAVES - 1) / PWAVES)  // 49
__global__ void pool_kernel(const float* __restrict__ h, const int* __restrict__ batching,
                            float* __restrict__ pooled, float* __restrict__ cnt) {
    int wid = (int)((blockIdx.x * (unsigned)blockDim.x + threadIdx.x) >> 6);
    int lane = threadIdx.x & 63;
    int start = wid * NPW;
    if (start >= NN) return;
    int end = min(start + NPW, NN);
    int g = batching[start];
    float acc = 0.f, c = 0.f;
    for (int i = start; i < end; i++) {
        int gi = batching[i];
        if (gi != g) {
            atomicAdd(&pooled[g * 64 + lane], acc);
            if (lane == 0) atomicAdd(&cnt[g], c);
            g = gi; acc = 0.f; c = 0.f;
        }
        acc += h[(size_t)i * 64 + lane];
        c += 1.f;
    }
    atomicAdd(&pooled[g * 64 + lane], acc);
    if (lane == 0) atomicAdd(&cnt[g], c);
}

// ---------- heads: two 64->64->64->2 MLPs per graph ----------
__global__ void head_kernel(const float* __restrict__ pooled, const float* __restrict__ cnt,
                            const float* pw1, const float* pb1, const float* pw2, const float* pb2,
                            const float* pw3, const float* pb3,
                            const float* tw1, const float* tb1, const float* tw2, const float* tb2,
                            const float* tw3, const float* tb3,
                            float* __restrict__ out) {
    int g = blockIdx.x, f = threadIdx.x;  // 64 threads
    __shared__ float pm[64], t1[64], t2[64];
    float c = cnt[g];
    if (c < 1.f) c = 1.f;
    pm[f] = pooled[g * 64 + f] / c;
    __syncthreads();
    float a = pb1[f];
    for (int j = 0; j < 64; j++) a += pm[j] * pw1[j * 64 + f];
    t1[f] = leaky(a);
    __syncthreads();
    a = pb2[f];
    for (int j = 0; j < 64; j++) a += t1[j] * pw2[j * 64 + f];
    t2[f] = leaky(a);
    __syncthreads();
    if (f < 2) {
        float o = pb3[f];
        for (int j = 0; j < 64; j++) o += t2[j] * pw3[j * 2 + f];
        out[g * 4 + f] = o;
    }
    __syncthreads();
    a = tb1[f];
    for (int j = 0; j < 64; j++) a += pm[j] * tw1[j * 64 + f];
    t1[f] = leaky(a);
    __syncthreads();
    a = tb2[f];
    for (int j = 0; j < 64; j++) a += t1[j] * tw2[j * 64 + f];
    t2[f] = leaky(a);
    __syncthreads();
    if (f < 2) {
        float o = tb3[f];
        for (int j = 0; j < 64; j++) o += t2[j] * tw3[j * 2 + f];
        out[g * 4 + 2 + f] = o;
    }
}

extern "C" void kernel_launch(void* const* d_in, const int* in_sizes, int n_in,
                              void* d_out, int out_size, void* d_ws, size_t ws_size,
                              hipStream_t stream) {
    const float* X = (const float*)d_in[0];
    const int* ei = (const int*)d_in[1];  // [2][E]
    const float* ew = (const float*)d_in[2];
    const int* batching = (const int*)d_in[3];
    const float* c1w = (const float*)d_in[4];
    const float* c1b = (const float*)d_in[5];
    const float* c2w = (const float*)d_in[6];
    const float* c2b = (const float*)d_in[7];
    const float* pw1 = (const float*)d_in[8];
    const float* pb1 = (const float*)d_in[9];
    const float* pw2 = (const float*)d_in[10];
    const float* pb2 = (const float*)d_in[11];
    const float* pw3 = (const float*)d_in[12];
    const float* pb3 = (const float*)d_in[13];
    const float* tw1 = (const float*)d_in[14];
    const float* tb1 = (const float*)d_in[15];
    const float* tw2 = (const float*)d_in[16];
    const float* tb2 = (const float*)d_in[17];
    const float* tw3 = (const float*)d_in[18];
    const float* tb3 = (const float*)d_in[19];
    float* out = (float*)d_out;

    const int* src = ei;
    const int* dst = ei + EE;

    // ---- workspace layout ----
    char* base = (char*)d_ws;
    int* cnt = (int*)base;                 // NN
    int* rowptr = cnt + NN;                // NN+1
    int* cursor = rowptr + NN + 1;         // NN
    int* blksum = cursor + NN;             // NBLK
    size_t off = (((size_t)(3 * NN + 1 + NBLK) * 4) + 15) & ~(size_t)15;
    float2* pairs = (float2*)(base + off);     // EE (12.8 MB, 16B-aligned)
    float* dis = (float*)(pairs + EE);         // NN
    float* selfn = dis + NN;                   // NN
    float* x1 = selfn + NN;                    // NN*3
    float* x2 = x1 + NN * 3;                   // NN*3
    float* x3 = x2 + NN * 3;                   // NN*3
    float* o2 = x3 + NN * 3;                   // NN*64 f32
    float* pooled = o2 + (size_t)NN * 64;      // GG*64
    float* cntf = pooled + GG * 64;            // GG
    bf16* hb0 = (bf16*)(cntf + GG);            // NN*64 bf16 (16B-aligned: all prior sizes are)
    bf16* hb1 = hb0 + (size_t)NN * 64;
    bf16* hb2 = hb1 + (size_t)NN * 64;
    bf16* hb3 = hb2 + (size_t)NN * 64;

    // ---- init ----
    zero_int_kernel<<<512, 256, 0, stream>>>(cnt, NN);
    fill_kernel<<<64, 256, 0, stream>>>(pooled, 0.0f, GG * 64 + GG);

    // ---- CSR build (by dst) ----
    hist_kernel<<<2048, 256, 0, stream>>>(dst, cnt);
    scan_block_kernel<<<NBLK, SCAN_BS, 0, stream>>>(cnt, rowptr, blksum);
    scan_top_kernel<<<1, 128, 0, stream>>>(blksum);
    scan_add_kernel<<<392, 256, 0, stream>>>(rowptr, blksum, cursor);
    build_kernel<<<2048, 256, 0, stream>>>(src, dst, ew, cursor, pairs);

    // ---- gcn_norm over CSR ----
    node_dis_kernel<<<392, 256, 0, stream>>>(rowptr, pairs, dis, selfn);
    node_nrm_kernel<<<392, 256, 0, stream>>>(rowptr, pairs, dis);

    // ---- layer 1 hops (F=3, f32) ----
    gather3_kernel<<<392, 256, 0, stream>>>(rowptr, pairs, selfn, X, x1);
    gather3_kernel<<<392, 256, 0, stream>>>(rowptr, pairs, selfn, x1, x2);
    gather3_kernel<<<392, 256, 0, stream>>>(rowptr, pairs, selfn, x2, x3);
    l1_out<<<NN / 32, 256, 0, stream>>>(X, x1, x2, x3, c1w, c1b, hb0);

    // ---- layer 2 hops (F=64, bf16 rows) ----
    gather64b_kernel<<<25000, 256, 0, stream>>>(rowptr, pairs, selfn, hb0, hb1);
    gather64b_kernel<<<25000, 256, 0, stream>>>(rowptr, pairs, selfn, hb1, hb2);
    gather64b_kernel<<<25000, 256, 0, stream>>>(rowptr, pairs, selfn, hb2, hb3);
    l2_mfma<<<(NN + 63) / 64, 256, 0, stream>>>(hb0, hb1, hb2, hb3, c2w, c2b, o2);

    // ---- pool + heads ----
    pool_kernel<<<PWAVES / 4, 256, 0, stream>>>(o2, batching, pooled, cntf);
    head_kernel<<<GG, 64, 0, stream>>>(pooled, cntf, pw1, pb1, pw2, pb2, pw3, pb3,
                                       tw1, tb1, tw2, tb2, tw3, tb3, out);
}